// Round 2
// baseline (31.665 us; speedup 1.0000x reference)
//
#include <hip/hip_runtime.h>

#define KG 16          // gaussians per row
#define PROW (7 * KG)  // 112 floats per (b, ch) row
#define PPT 4          // pixels per thread (render kernel)

#if defined(__has_builtin) && __has_builtin(__builtin_amdgcn_exp2f)
#define EXP2F(x) __builtin_amdgcn_exp2f(x)
#else
#define EXP2F(x) exp2f(x)
#endif

// ---------------- kernel 1: per-(a,k) quadratic coefficients ----------------
// coef[(a*KG+k)*8 + {0..6}] = {Cxx, Cxy, Cyy, Cx, Cy, C0, w}
// E2 = Cxx*gx^2 + Cxy*gx*gy + Cyy*gy^2 + Cx*gx + Cy*gy + C0  (log2-domain)
__global__ void moe_coef_kernel(const float* __restrict__ params,
                                float* __restrict__ coef)
{
    const int a = blockIdx.x;
    const int k = threadIdx.x;     // 0..KG-1
    const float* p = params + (size_t)a * PROW;

    const float mx = p[k];
    const float my = p[KG + k];
    const float s00 = p[3 * KG + 4 * k + 0];
    const float s10 = p[3 * KG + 4 * k + 2];
    const float s11 = p[3 * KG + 4 * k + 3];
    // sigma = L L^T (L = tril); srow = row-sums of sigma
    const float s0 = s00 * s00 + s00 * s10;
    const float s1 = s10 * s00 + s10 * s10 + s11 * s11;

    // softmax over the K logits
    float m = -INFINITY;
    #pragma unroll
    for (int j = 0; j < KG; ++j) m = fmaxf(m, p[2 * KG + j]);
    float den = 0.0f;
    #pragma unroll
    for (int j = 0; j < KG; ++j) den += __expf(p[2 * KG + j] - m);
    const float w = __expf(p[2 * KG + k] - m) / den;

    // exponent: -0.5*(s0*dx^2 + (s0+s1)*dx*dy + s1*dy^2), dx=gx-mx, dy=gy-my
    // expanded & scaled to log2 domain: Q = -0.5*log2(e)
    const float Q = -0.72134752044448170368f;
    const float sxy = s0 + s1;
    float* c = coef + ((size_t)a * KG + k) * 8;
    c[0] = Q * s0;                                        // gx^2
    c[1] = Q * sxy;                                       // gx*gy
    c[2] = Q * s1;                                        // gy^2
    c[3] = Q * (-2.0f * s0 * mx - sxy * my);              // gx
    c[4] = Q * (-2.0f * s1 * my - sxy * mx);              // gy
    c[5] = Q * (s0 * mx * mx + sxy * mx * my + s1 * my * my); // 1
    c[6] = w;
    c[7] = 0.0f;
}

// ---------------- kernel 2: render, 4 pixels/thread, float4 store ----------
__global__ __launch_bounds__(256) void moe_render_kernel(
    const float* __restrict__ coef,
    const int* __restrict__ hptr,
    const int* __restrict__ wptr,
    float* __restrict__ out,
    int N)
{
    const int a = blockIdx.y;
    const int H = *hptr;
    const int W = *wptr;
    const int base = (blockIdx.x * 256 + threadIdx.x) * PPT;
    if (base >= N) return;

    const float* __restrict__ c = coef + (size_t)a * KG * 8;  // wave-uniform
    const float invW = 1.0f / (float)(W - 1);
    const float invH = 1.0f / (float)(H - 1);

    // grid[n] = (xx[n / H], yy[n % H])
    const unsigned uH = (unsigned)H;
    unsigned i0 = (unsigned)base / uH;
    unsigned j0 = (unsigned)base - i0 * uH;

    float gx[PPT], gy[PPT], gx2[PPT], gxy[PPT], gy2[PPT];
    #pragma unroll
    for (int t = 0; t < PPT; ++t) {
        unsigned jt = j0 + (unsigned)t;
        unsigned it = i0;
        if (jt >= uH) { jt -= uH; it += 1; }   // PPT <= H assumed
        const float x = (float)it * invW;
        const float y = (float)jt * invH;
        gx[t] = x; gy[t] = y;
        gx2[t] = x * x; gxy[t] = x * y; gy2[t] = y * y;
    }

    float es[PPT], ws[PPT];
    #pragma unroll
    for (int t = 0; t < PPT; ++t) { es[t] = 0.0f; ws[t] = 0.0f; }

    #pragma unroll
    for (int k = 0; k < KG; ++k) {
        const float Cxx = c[k * 8 + 0];
        const float Cxy = c[k * 8 + 1];
        const float Cyy = c[k * 8 + 2];
        const float Cx  = c[k * 8 + 3];
        const float Cy  = c[k * 8 + 4];
        const float C0  = c[k * 8 + 5];
        const float wk  = c[k * 8 + 6];
        #pragma unroll
        for (int t = 0; t < PPT; ++t) {
            float E = fmaf(Cy, gy[t], C0);
            E = fmaf(Cx, gx[t], E);
            E = fmaf(Cyy, gy2[t], E);
            E = fmaf(Cxy, gxy[t], E);
            E = fmaf(Cxx, gx2[t], E);
            const float e = EXP2F(E);
            es[t] += e;
            ws[t] = fmaf(wk, e, ws[t]);
        }
    }

    float4 r;
    float* rp = &r.x;
    #pragma unroll
    for (int t = 0; t < PPT; ++t) {
        const float g = fmaxf(es[t], 1e-8f);
        float y = ws[t] / g;
        rp[t] = fminf(fmaxf(y, 0.0f), 1.0f);
    }

    if (base + PPT <= N) {
        *reinterpret_cast<float4*>(out + (size_t)a * (size_t)N + base) = r;
    } else {
        for (int t = 0; t < PPT && base + t < N; ++t)
            out[(size_t)a * (size_t)N + base + t] = rp[t];
    }
}

// ---------------- fallback single kernel (if ws too small) ------------------
__global__ __launch_bounds__(256) void moe_fallback_kernel(
    const float* __restrict__ params,
    const int* __restrict__ hptr,
    const int* __restrict__ wptr,
    float* __restrict__ out,
    int N)
{
    const int a = blockIdx.y;
    const int H = *hptr;
    const int W = *wptr;
    const int n = blockIdx.x * blockDim.x + threadIdx.x;

    __shared__ float smux[KG], smuy[KG], ss0[KG], ss1[KG], swt[KG];
    if (threadIdx.x < KG) {
        const int k = threadIdx.x;
        const float* p = params + (size_t)a * PROW;
        const float s00 = p[3 * KG + 4 * k + 0];
        const float s10 = p[3 * KG + 4 * k + 2];
        const float s11 = p[3 * KG + 4 * k + 3];
        float m = -INFINITY;
        for (int j = 0; j < KG; ++j) m = fmaxf(m, p[2 * KG + j]);
        float den = 0.0f;
        for (int j = 0; j < KG; ++j) den += __expf(p[2 * KG + j] - m);
        smux[k] = p[k];
        smuy[k] = p[KG + k];
        ss0[k] = s00 * s00 + s00 * s10;
        ss1[k] = s10 * s00 + s10 * s10 + s11 * s11;
        swt[k] = __expf(p[2 * KG + k] - m) / den;
    }
    __syncthreads();
    if (n >= N) return;

    const int i = n / H;
    const int j = n - i * H;
    const float gx = (float)i / (float)(W - 1);
    const float gy = (float)j / (float)(H - 1);

    float esum = 0.0f, wsum = 0.0f;
    #pragma unroll
    for (int k = 0; k < KG; ++k) {
        const float dx = gx - smux[k];
        const float dy = gy - smuy[k];
        const float t1 = dx * ss0[k] + dy * ss1[k];
        const float t2 = dx + dy;
        const float e = __expf(-0.5f * t1 * t2);
        esum += e;
        wsum = fmaf(swt[k], e, wsum);
    }
    float y = wsum / fmaxf(esum, 1e-8f);
    out[(size_t)a * (size_t)N + n] = fminf(fmaxf(y, 0.0f), 1.0f);
}

extern "C" void kernel_launch(void* const* d_in, const int* in_sizes, int n_in,
                              void* d_out, int out_size, void* d_ws, size_t ws_size,
                              hipStream_t stream) {
    const float* params = (const float*)d_in[0];
    const int* hptr = (const int*)d_in[1];
    const int* wptr = (const int*)d_in[2];
    float* out = (float*)d_out;

    const int A = in_sizes[0] / PROW;   // B*CH = 24
    const int N = out_size / A;         // H*W = 65536

    const size_t coef_bytes = (size_t)A * KG * 8 * sizeof(float);
    if (ws_size >= coef_bytes) {
        float* coef = (float*)d_ws;
        moe_coef_kernel<<<dim3(A), dim3(KG), 0, stream>>>(params, coef);
        dim3 block(256);
        dim3 grid((N + 256 * PPT - 1) / (256 * PPT), A);
        moe_render_kernel<<<grid, block, 0, stream>>>(coef, hptr, wptr, out, N);
    } else {
        dim3 block(256);
        dim3 grid((N + 255) / 256, A);
        moe_fallback_kernel<<<grid, block, 0, stream>>>(params, hptr, wptr, out, N);
    }
}

// Round 3
// 12.149 us; speedup vs baseline: 2.6063x; 2.6063x over previous
//
#include <hip/hip_runtime.h>

#define KG 16          // gaussians per row
#define PROW (7 * KG)  // 112 floats per (b, ch) row
#define PPT 8          // pixels per thread
#define BLK 256

#if defined(__has_builtin) && __has_builtin(__builtin_amdgcn_exp2f)
#define EXP2F(x) __builtin_amdgcn_exp2f(x)
#else
#define EXP2F(x) exp2f(x)
#endif
#if defined(__has_builtin) && __has_builtin(__builtin_amdgcn_rcpf)
#define RCPF(x) __builtin_amdgcn_rcpf(x)
#else
#define RCPF(x) (1.0f / (x))
#endif

// Single fused kernel. Per-block preamble (16 threads) computes, per gaussian
// k, the expanded quadratic in the log2 domain:
//   E(gx,gy) = Cxx gx^2 + Cxy gx gy + Cyy gy^2 + Cx gx + Cy gy + C0
// so e = exp2(E). Main loop walks 8 consecutive pixels (= consecutive gy at
// fixed gx, since grid[n] = (xx[n/H], yy[n%H])) via forward differencing:
//   E_{t+1} = E_t + d1,  d1_{t+1} = d1 + dd,  dd = 2 Cyy dY^2.
__global__ __launch_bounds__(BLK) void moe_fused_kernel(
    const float* __restrict__ params,
    const int* __restrict__ hptr,
    const int* __restrict__ wptr,
    float* __restrict__ out,
    int N)
{
    const int a = blockIdx.y;
    const int H = *hptr;
    const int W = *wptr;
    const float dY = 1.0f / (float)(H - 1);
    const float invW = 1.0f / (float)(W - 1);

    __shared__ float sc[KG][8];  // {Cxx,Cxy,Cyy,Cx,Cy,C0,w,dd}

    if (threadIdx.x < KG) {
        const int k = threadIdx.x;
        const float* p = params + (size_t)a * PROW;
        const float mx = p[k];
        const float my = p[KG + k];
        const float s00 = p[3 * KG + 4 * k + 0];
        const float s10 = p[3 * KG + 4 * k + 2];
        const float s11 = p[3 * KG + 4 * k + 3];
        // sigma = L L^T (L = tril); srow = row sums
        const float s0 = s00 * s00 + s00 * s10;
        const float s1 = s10 * s00 + s10 * s10 + s11 * s11;

        // softmax over K logits: each lane holds one logit, shfl-reduce
        const float lk = p[2 * KG + k];
        float m = lk;
        #pragma unroll
        for (int off = 1; off < KG; off <<= 1) m = fmaxf(m, __shfl_xor(m, off, 64));
        const float ek = __expf(lk - m);
        float den = ek;
        #pragma unroll
        for (int off = 1; off < KG; off <<= 1) den += __shfl_xor(den, off, 64);
        const float wk = ek / den;

        const float Q = -0.72134752044448170368f;  // -0.5 * log2(e)
        const float sxy = s0 + s1;
        const float Cyy = Q * s1;
        sc[k][0] = Q * s0;
        sc[k][1] = Q * sxy;
        sc[k][2] = Cyy;
        sc[k][3] = Q * (-2.0f * s0 * mx - sxy * my);
        sc[k][4] = Q * (-2.0f * s1 * my - sxy * mx);
        sc[k][5] = Q * (s0 * mx * mx + sxy * mx * my + s1 * my * my);
        sc[k][6] = wk;
        sc[k][7] = 2.0f * Cyy * dY * dY;
    }
    __syncthreads();

    const int base = (blockIdx.x * BLK + threadIdx.x) * PPT;
    if (base >= N) return;

    const unsigned uH = (unsigned)H;
    const unsigned i0 = (unsigned)base / uH;
    const unsigned j0 = (unsigned)base - i0 * uH;
    const float gx = (float)i0 * invW;
    const float gy0 = (float)j0 * dY;

    if (base + PPT <= N && j0 + PPT <= uH) {
        // fast path: all 8 pixels share gx, consecutive gy
        const float gx2 = gx * gx;
        const float gy02 = gy0 * gy0;
        const float ty = dY * (2.0f * gy0 + dY);  // E(y+dY)-E(y) quad part / Cyy

        float es[PPT], ws[PPT];
        #pragma unroll
        for (int t = 0; t < PPT; ++t) { es[t] = 0.0f; ws[t] = 0.0f; }

        #pragma unroll
        for (int k = 0; k < KG; ++k) {
            const float Cxx = sc[k][0], Cxy = sc[k][1], Cyy = sc[k][2];
            const float Cx = sc[k][3], Cy = sc[k][4], C0 = sc[k][5];
            const float wk = sc[k][6], dd = sc[k][7];
            const float B = fmaf(Cxy, gx, Cy);
            float E = fmaf(Cyy, gy02,
                      fmaf(B, gy0, fmaf(Cxx, gx2, fmaf(Cx, gx, C0))));
            float d1 = fmaf(Cyy, ty, B * dY);
            #pragma unroll
            for (int t = 0; t < PPT; ++t) {
                const float e = EXP2F(E);
                es[t] += e;
                ws[t] = fmaf(wk, e, ws[t]);
                if (t < PPT - 1) { E += d1; d1 += dd; }
            }
        }

        float r[PPT];
        #pragma unroll
        for (int t = 0; t < PPT; ++t) {
            const float g = fmaxf(es[t], 1e-8f);
            const float y = ws[t] * RCPF(g);
            r[t] = fminf(fmaxf(y, 0.0f), 1.0f);
        }
        float4* o = reinterpret_cast<float4*>(out + (size_t)a * (size_t)N + base);
        o[0] = make_float4(r[0], r[1], r[2], r[3]);
        o[1] = make_float4(r[4], r[5], r[6], r[7]);
    } else {
        // slow path: column crossing or tail — direct eval per pixel
        for (int t = 0; t < PPT && base + t < N; ++t) {
            const unsigned n = (unsigned)(base + t);
            const unsigned it = n / uH;
            const unsigned jt = n - it * uH;
            const float x = (float)it * invW;
            const float yv = (float)jt * dY;
            float esum = 0.0f, wsum = 0.0f;
            #pragma unroll
            for (int k = 0; k < KG; ++k) {
                const float E = fmaf(sc[k][2], yv * yv,
                                fmaf(fmaf(sc[k][1], x, sc[k][4]), yv,
                                fmaf(sc[k][0], x * x, fmaf(sc[k][3], x, sc[k][5]))));
                const float e = EXP2F(E);
                esum += e;
                wsum = fmaf(sc[k][6], e, wsum);
            }
            const float y = wsum * RCPF(fmaxf(esum, 1e-8f));
            out[(size_t)a * (size_t)N + n] = fminf(fmaxf(y, 0.0f), 1.0f);
        }
    }
}

extern "C" void kernel_launch(void* const* d_in, const int* in_sizes, int n_in,
                              void* d_out, int out_size, void* d_ws, size_t ws_size,
                              hipStream_t stream) {
    const float* params = (const float*)d_in[0];
    const int* hptr = (const int*)d_in[1];
    const int* wptr = (const int*)d_in[2];
    float* out = (float*)d_out;

    const int A = in_sizes[0] / PROW;   // B*CH = 24
    const int N = out_size / A;         // H*W = 65536

    dim3 block(BLK);
    dim3 grid((N + BLK * PPT - 1) / (BLK * PPT), A);
    moe_fused_kernel<<<grid, block, 0, stream>>>(params, hptr, wptr, out, N);
}